// Round 1
// baseline (325.880 us; speedup 1.0000x reference)
//
#include <hip/hip_runtime.h>
#include <hip/hip_bf16.h>
#include <math.h>

// ---------------------------------------------------------------------------
// AdderNet LeNet forward:
//   adder1 [128,1,28,28]x[20,1,5,5] -> [128,20,24,24]
//   BN(train, biased var) -> maxpool2x2 -> [128,20,12,12]
//   adder2 x[50,20,5,5] -> [128,50,8,8]
//   BN -> maxpool2x2 -> [128,50,4,4] == [128,800]
//   fc1(800->500)+relu, fc2(500->10)+bias, softmax -> [128,10]
// ---------------------------------------------------------------------------

#define B_N 128

// ---- adder conv 1: x[128,1,28,28], w[20,1,5,5] -> h[128,20,24,24] ----------
__global__ __launch_bounds__(256) void adder1_kernel(
    const float* __restrict__ x, const float* __restrict__ w1,
    float* __restrict__ out) {
  __shared__ float ws[512];
  for (int i = threadIdx.x; i < 500; i += 256) ws[i] = w1[i];
  __syncthreads();
  int idx = blockIdx.x * 256 + threadIdx.x;   // grid exact: 1474560 = 5760*256
  int ow = idx % 24; int t = idx / 24;
  int oh = t % 24;   t /= 24;
  int o  = t % 20;   int b = t / 20;
  const float* xp = x + b * 784 + oh * 28 + ow;
  const float* wp = ws + o * 25;
  float s = 0.f;
#pragma unroll
  for (int kh = 0; kh < 5; ++kh)
#pragma unroll
    for (int kw = 0; kw < 5; ++kw)
      s += fabsf(xp[kh * 28 + kw] - wp[kh * 5 + kw]);
  out[idx] = -s;
}

// ---- BN stats: one block per channel; emits scale=g*inv, bias=b-mean*scale -
__global__ __launch_bounds__(256) void bn_stats_kernel(
    const float* __restrict__ h, int C, int HW,
    const float* __restrict__ gamma, const float* __restrict__ beta,
    float* __restrict__ scale, float* __restrict__ bias) {
  const int c = blockIdx.x;
  float s = 0.f, s2 = 0.f;
  for (int b = 0; b < B_N; ++b) {
    const float* hp = h + (b * C + c) * HW;
    for (int p = threadIdx.x; p < HW; p += 256) {
      float v = hp[p];
      s += v; s2 += v * v;
    }
  }
  __shared__ float ls[256], ls2[256];
  ls[threadIdx.x] = s; ls2[threadIdx.x] = s2;
  __syncthreads();
  for (int off = 128; off > 0; off >>= 1) {
    if (threadIdx.x < off) {
      ls[threadIdx.x]  += ls[threadIdx.x + off];
      ls2[threadIdx.x] += ls2[threadIdx.x + off];
    }
    __syncthreads();
  }
  if (threadIdx.x == 0) {
    float n    = (float)(B_N * HW);
    float mean = ls[0] / n;
    float var  = ls2[0] / n - mean * mean;
    float inv  = rsqrtf(var + 1e-5f);
    float sc   = gamma[c] * inv;
    scale[c] = sc;
    bias[c]  = beta[c] - mean * sc;
  }
}

// ---- BN apply + 2x2 maxpool ------------------------------------------------
__global__ __launch_bounds__(256) void bn_pool_kernel(
    const float* __restrict__ h, const float* __restrict__ scale,
    const float* __restrict__ bias, float* __restrict__ out,
    int C, int Hin, int Hout) {
  int idx = blockIdx.x * 256 + threadIdx.x;   // grids exact multiples of 256
  int total = B_N * C * Hout * Hout;
  if (idx >= total) return;
  int pw = idx % Hout; int t = idx / Hout;
  int ph = t % Hout;   t /= Hout;
  int c  = t % C;      int b = t / C;
  const float* hp = h + ((b * C + c) * Hin + 2 * ph) * Hin + 2 * pw;
  float sc = scale[c], bi = bias[c];
  float v0 = fmaf(sc, hp[0],        bi);
  float v1 = fmaf(sc, hp[1],        bi);
  float v2 = fmaf(sc, hp[Hin],     bi);
  float v3 = fmaf(sc, hp[Hin + 1], bi);
  out[idx] = fmaxf(fmaxf(v0, v1), fmaxf(v2, v3));
}

// ---- adder conv 2: h[128,20,12,12], w[50,20,5,5] -> [128,50,8,8] -----------
__global__ __launch_bounds__(256) void adder2_kernel(
    const float* __restrict__ h, const float* __restrict__ w2,
    float* __restrict__ out) {
  int idx = blockIdx.x * 256 + threadIdx.x;   // 409600 = 1600*256
  int ow = idx % 8; int t = idx / 8;
  int oh = t % 8;   t /= 8;
  int o  = t % 50;  int b = t / 50;
  // within a wave: 64 lanes == one full 8x8 plane for a single (b,o)
  const float* hb = h + b * (20 * 144) + oh * 12 + ow;
  const float* wb = w2 + o * 500;
  float s = 0.f;
  for (int c = 0; c < 20; ++c) {
    const float* hp = hb + c * 144;
    const float* wp = wb + c * 25;
#pragma unroll
    for (int kh = 0; kh < 5; ++kh)
#pragma unroll
      for (int kw = 0; kw < 5; ++kw)
        s += fabsf(hp[kh * 12 + kw] - wp[kh * 5 + kw]);
  }
  out[idx] = -s;
}

// ---- fused FC head: fc1+relu, fc2+bias, softmax; one block per image -------
__global__ __launch_bounds__(256) void fc_head_kernel(
    const float* __restrict__ h,    // [128,800]
    const float* __restrict__ w1, const float* __restrict__ b1,  // [500,800],[500]
    const float* __restrict__ w2, const float* __restrict__ b2,  // [10,500],[10]
    float* __restrict__ out) {      // [128,10]
  __shared__ float feat[800];
  __shared__ float hid[512];
  __shared__ float logit[16];
  const int b = blockIdx.x;
  for (int i = threadIdx.x; i < 800; i += 256) feat[i] = h[b * 800 + i];
  __syncthreads();
  for (int j = threadIdx.x; j < 500; j += 256) {
    const float* wr = w1 + j * 800;
    float acc = b1[j];
    for (int k = 0; k < 800; k += 4) {
      float4 w4 = *(const float4*)(wr + k);
      acc += feat[k] * w4.x + feat[k + 1] * w4.y +
             feat[k + 2] * w4.z + feat[k + 3] * w4.w;
    }
    hid[j] = fmaxf(acc, 0.f);
  }
  __syncthreads();
  const int wave = threadIdx.x >> 6, lane = threadIdx.x & 63;
  for (int j = wave; j < 10; j += 4) {
    const float* wr = w2 + j * 500;
    float acc = 0.f;
    for (int k = lane; k < 500; k += 64) acc += hid[k] * wr[k];
#pragma unroll
    for (int off = 32; off > 0; off >>= 1) acc += __shfl_down(acc, off);
    if (lane == 0) logit[j] = acc + b2[j];
  }
  __syncthreads();
  if (threadIdx.x == 0) {
    float m = logit[0];
    for (int j = 1; j < 10; ++j) m = fmaxf(m, logit[j]);
    float s = 0.f, e[10];
    for (int j = 0; j < 10; ++j) { e[j] = __expf(logit[j] - m); s += e[j]; }
    float inv = 1.f / s;
    for (int j = 0; j < 10; ++j) out[b * 10 + j] = e[j] * inv;
  }
}

extern "C" void kernel_launch(void* const* d_in, const int* in_sizes, int n_in,
                              void* d_out, int out_size, void* d_ws, size_t ws_size,
                              hipStream_t stream) {
  const float* x   = (const float*)d_in[0];   // [128,1,28,28]
  const float* w1  = (const float*)d_in[1];   // [20,1,5,5]
  const float* g1  = (const float*)d_in[2];   // [20]
  const float* be1 = (const float*)d_in[3];   // [20]
  const float* w2  = (const float*)d_in[4];   // [50,20,5,5]
  const float* g2  = (const float*)d_in[5];   // [50]
  const float* be2 = (const float*)d_in[6];   // [50]
  const float* fw1 = (const float*)d_in[7];   // [500,800]
  const float* fb1 = (const float*)d_in[8];   // [500]
  const float* fw2 = (const float*)d_in[9];   // [10,500]
  const float* fb2 = (const float*)d_in[10];  // [10]
  float* out = (float*)d_out;

  // workspace layout (floats); h2 reuses h1's region (h1 dead after pool1)
  float* ws   = (float*)d_ws;
  float* h1   = ws;                 // [0, 1474560)           128*20*24*24
  float* h1p  = ws + 1474560;       // [1474560, 1843200)     128*20*12*12
  float* h2   = ws;                 // reuse: [0, 409600)     128*50*8*8
  float* h2p  = ws + 409600;        // [409600, 512000)       128*50*4*4 (inside h1 region, h1 dead)
  float* bn1s = ws + 1843200;       // small BN param scratch
  float* bn1b = bn1s + 32;
  float* bn2s = bn1b + 32;
  float* bn2b = bn2s + 64;

  adder1_kernel<<<5760, 256, 0, stream>>>(x, w1, h1);
  bn_stats_kernel<<<20, 256, 0, stream>>>(h1, 20, 576, g1, be1, bn1s, bn1b);
  bn_pool_kernel<<<1440, 256, 0, stream>>>(h1, bn1s, bn1b, h1p, 20, 24, 12);
  adder2_kernel<<<1600, 256, 0, stream>>>(h1p, w2, h2);
  bn_stats_kernel<<<50, 256, 0, stream>>>(h2, 50, 64, g2, be2, bn2s, bn2b);
  bn_pool_kernel<<<400, 256, 0, stream>>>(h2, bn2s, bn2b, h2p, 50, 8, 4);
  fc_head_kernel<<<128, 256, 0, stream>>>(h2p, fw1, fb1, fw2, fb2, out);
}

// Round 2
// 208.654 us; speedup vs baseline: 1.5618x; 1.5618x over previous
//
#include <hip/hip_runtime.h>
#include <hip/hip_bf16.h>
#include <math.h>

// ---------------------------------------------------------------------------
// AdderNet LeNet forward:
//   adder1 [128,1,28,28]x[20,1,5,5] -> [128,20,24,24]
//   BN(train, biased var) -> maxpool2x2 -> [128,20,12,12]
//   adder2 x[50,20,5,5] -> [128,50,8,8]
//   BN -> maxpool2x2 -> [128,50,4,4] == [128,800]
//   fc1(800->500)+relu, fc2(500->10)+bias, softmax -> [128,10]
// R1: bn_stats (20-block serial reduce, 102us) replaced by many-block
//     bn_partial + atomicAdd accumulators; scale/bias finalized inline
//     in bn_pool. Accumulators zeroed via hipMemsetAsync on stream.
// ---------------------------------------------------------------------------

#define B_N 128
#define EPSBN 1e-5f

// ---- adder conv 1: x[128,1,28,28], w[20,1,5,5] -> h[128,20,24,24] ----------
__global__ __launch_bounds__(256) void adder1_kernel(
    const float* __restrict__ x, const float* __restrict__ w1,
    float* __restrict__ out) {
  __shared__ float ws[512];
  for (int i = threadIdx.x; i < 500; i += 256) ws[i] = w1[i];
  __syncthreads();
  int idx = blockIdx.x * 256 + threadIdx.x;   // grid exact: 1474560 = 5760*256
  int ow = idx % 24; int t = idx / 24;
  int oh = t % 24;   t /= 24;
  int o  = t % 20;   int b = t / 20;
  const float* xp = x + b * 784 + oh * 28 + ow;
  const float* wp = ws + o * 25;
  float s = 0.f;
#pragma unroll
  for (int kh = 0; kh < 5; ++kh)
#pragma unroll
    for (int kw = 0; kw < 5; ++kw)
      s += fabsf(xp[kh * 28 + kw] - wp[kh * 5 + kw]);
  out[idx] = -s;
}

// ---- BN partial sums: grid = C*slices blocks; atomicAdd into sums[2*C] -----
// sums[2c] = sum, sums[2c+1] = sumsq. HW must be divisible by 4 (576, 64 ok).
__global__ __launch_bounds__(256) void bn_partial_kernel(
    const float* __restrict__ h, int C, int HW4, int bPerSlice,
    float* __restrict__ sums) {
  const int c = blockIdx.x % C;
  const int slice = blockIdx.x / C;
  const int b0 = slice * bPerSlice;
  float s = 0.f, s2 = 0.f;
  for (int b = b0; b < b0 + bPerSlice; ++b) {
    const float4* hp = (const float4*)(h + (size_t)(b * C + c) * (HW4 * 4));
    for (int p = threadIdx.x; p < HW4; p += 256) {
      float4 v = hp[p];
      s  += v.x + v.y + v.z + v.w;
      s2 += v.x * v.x + v.y * v.y + v.z * v.z + v.w * v.w;
    }
  }
  __shared__ float ls[256], ls2[256];
  ls[threadIdx.x] = s; ls2[threadIdx.x] = s2;
  __syncthreads();
  for (int off = 128; off > 0; off >>= 1) {
    if (threadIdx.x < off) {
      ls[threadIdx.x]  += ls[threadIdx.x + off];
      ls2[threadIdx.x] += ls2[threadIdx.x + off];
    }
    __syncthreads();
  }
  if (threadIdx.x == 0) {
    atomicAdd(&sums[2 * c],     ls[0]);
    atomicAdd(&sums[2 * c + 1], ls2[0]);
  }
}

// ---- BN finalize (inline) + apply + 2x2 maxpool ----------------------------
__global__ __launch_bounds__(256) void bn_pool_kernel(
    const float* __restrict__ h, const float* __restrict__ sums,
    const float* __restrict__ gamma, const float* __restrict__ beta,
    float* __restrict__ out, int C, int Hin, int Hout, float inv_n) {
  int idx = blockIdx.x * 256 + threadIdx.x;   // grids exact multiples of 256
  int total = B_N * C * Hout * Hout;
  if (idx >= total) return;
  int pw = idx % Hout; int t = idx / Hout;
  int ph = t % Hout;   t /= Hout;
  int c  = t % C;      int b = t / C;
  float sm   = sums[2 * c];
  float s2   = sums[2 * c + 1];
  float mean = sm * inv_n;
  float var  = s2 * inv_n - mean * mean;
  float sc   = gamma[c] * rsqrtf(var + EPSBN);
  float bi   = beta[c] - mean * sc;
  const float* hp = h + ((b * C + c) * Hin + 2 * ph) * Hin + 2 * pw;
  float v0 = fmaf(sc, hp[0],       bi);
  float v1 = fmaf(sc, hp[1],       bi);
  float v2 = fmaf(sc, hp[Hin],     bi);
  float v3 = fmaf(sc, hp[Hin + 1], bi);
  out[idx] = fmaxf(fmaxf(v0, v1), fmaxf(v2, v3));
}

// ---- adder conv 2: h[128,20,12,12], w[50,20,5,5] -> [128,50,8,8] -----------
__global__ __launch_bounds__(256) void adder2_kernel(
    const float* __restrict__ h, const float* __restrict__ w2,
    float* __restrict__ out) {
  int idx = blockIdx.x * 256 + threadIdx.x;   // 409600 = 1600*256
  int ow = idx % 8; int t = idx / 8;
  int oh = t % 8;   t /= 8;
  int o  = t % 50;  int b = t / 50;
  // within a wave: 64 lanes == one full 8x8 plane for a single (b,o)
  const float* hb = h + b * (20 * 144) + oh * 12 + ow;
  const float* wb = w2 + o * 500;
  float s = 0.f;
  for (int c = 0; c < 20; ++c) {
    const float* hp = hb + c * 144;
    const float* wp = wb + c * 25;
#pragma unroll
    for (int kh = 0; kh < 5; ++kh)
#pragma unroll
      for (int kw = 0; kw < 5; ++kw)
        s += fabsf(hp[kh * 12 + kw] - wp[kh * 5 + kw]);
  }
  out[idx] = -s;
}

// ---- fused FC head: fc1+relu, fc2+bias, softmax; one block per image -------
__global__ __launch_bounds__(256) void fc_head_kernel(
    const float* __restrict__ h,    // [128,800]
    const float* __restrict__ w1, const float* __restrict__ b1,  // [500,800],[500]
    const float* __restrict__ w2, const float* __restrict__ b2,  // [10,500],[10]
    float* __restrict__ out) {      // [128,10]
  __shared__ float feat[800];
  __shared__ float hid[512];
  __shared__ float logit[16];
  const int b = blockIdx.x;
  for (int i = threadIdx.x; i < 800; i += 256) feat[i] = h[b * 800 + i];
  __syncthreads();
  for (int j = threadIdx.x; j < 500; j += 256) {
    const float* wr = w1 + j * 800;
    float acc = b1[j];
    for (int k = 0; k < 800; k += 4) {
      float4 w4 = *(const float4*)(wr + k);
      acc += feat[k] * w4.x + feat[k + 1] * w4.y +
             feat[k + 2] * w4.z + feat[k + 3] * w4.w;
    }
    hid[j] = fmaxf(acc, 0.f);
  }
  __syncthreads();
  const int wave = threadIdx.x >> 6, lane = threadIdx.x & 63;
  for (int j = wave; j < 10; j += 4) {
    const float* wr = w2 + j * 500;
    float acc = 0.f;
    for (int k = lane; k < 500; k += 64) acc += hid[k] * wr[k];
#pragma unroll
    for (int off = 32; off > 0; off >>= 1) acc += __shfl_down(acc, off);
    if (lane == 0) logit[j] = acc + b2[j];
  }
  __syncthreads();
  if (threadIdx.x == 0) {
    float m = logit[0];
    for (int j = 1; j < 10; ++j) m = fmaxf(m, logit[j]);
    float s = 0.f, e[10];
    for (int j = 0; j < 10; ++j) { e[j] = __expf(logit[j] - m); s += e[j]; }
    float inv = 1.f / s;
    for (int j = 0; j < 10; ++j) out[b * 10 + j] = e[j] * inv;
  }
}

extern "C" void kernel_launch(void* const* d_in, const int* in_sizes, int n_in,
                              void* d_out, int out_size, void* d_ws, size_t ws_size,
                              hipStream_t stream) {
  const float* x   = (const float*)d_in[0];   // [128,1,28,28]
  const float* w1  = (const float*)d_in[1];   // [20,1,5,5]
  const float* g1  = (const float*)d_in[2];   // [20]
  const float* be1 = (const float*)d_in[3];   // [20]
  const float* w2  = (const float*)d_in[4];   // [50,20,5,5]
  const float* g2  = (const float*)d_in[5];   // [50]
  const float* be2 = (const float*)d_in[6];   // [50]
  const float* fw1 = (const float*)d_in[7];   // [500,800]
  const float* fb1 = (const float*)d_in[8];   // [500]
  const float* fw2 = (const float*)d_in[9];   // [10,500]
  const float* fb2 = (const float*)d_in[10];  // [10]
  float* out = (float*)d_out;

  // workspace layout (floats); h2 reuses h1's region (h1 dead after pool1)
  float* ws   = (float*)d_ws;
  float* h1   = ws;                 // [0, 1474560)           128*20*24*24
  float* h1p  = ws + 1474560;       // [1474560, 1843200)     128*20*12*12
  float* h2   = ws;                 // reuse: [0, 409600)     128*50*8*8
  float* h2p  = ws + 409600;        // [409600, 512000)       inside dead h1 region
  float* sums1 = ws + 1843200;      // [2*20] BN1 sum/sumsq accumulators
  float* sums2 = sums1 + 40;        // [2*50]

  // zero the 140-float accumulator region (ws is re-poisoned to 0xAA each call)
  hipMemsetAsync(sums1, 0, 140 * sizeof(float), stream);

  adder1_kernel<<<5760, 256, 0, stream>>>(x, w1, h1);
  bn_partial_kernel<<<20 * 16, 256, 0, stream>>>(h1, 20, 144, 8, sums1);
  bn_pool_kernel<<<1440, 256, 0, stream>>>(h1, sums1, g1, be1, h1p, 20, 24, 12,
                                           1.f / (B_N * 576));
  adder2_kernel<<<1600, 256, 0, stream>>>(h1p, w2, h2);
  bn_partial_kernel<<<50 * 8, 256, 0, stream>>>(h2, 50, 16, 16, sums2);
  bn_pool_kernel<<<400, 256, 0, stream>>>(h2, sums2, g2, be2, h2p, 50, 8, 4,
                                          1.f / (B_N * 64));
  fc_head_kernel<<<128, 256, 0, stream>>>(h2p, fw1, fb1, fw2, fb2, out);
}

// Round 3
// 193.699 us; speedup vs baseline: 1.6824x; 1.0772x over previous
//
#include <hip/hip_runtime.h>
#include <hip/hip_bf16.h>
#include <math.h>

// ---------------------------------------------------------------------------
// AdderNet LeNet forward. R2: row-register-blocked adder convs (8/24-wide
// output rows per thread, float4 row loads, 5 ops/load vs 0.5), FC head split
// into coalesced fc1 (thread=(j,b), transposed features) + fc2/softmax.
// ---------------------------------------------------------------------------

#define B_N 128
#define EPSBN 1e-5f

// ---- adder conv 1: x[128,1,28,28], w[20,1,5,5] -> h[128,20,24,24] ----------
// thread = (b,o,oh), computes 24 outputs (full ow row).
__global__ __launch_bounds__(256) void adder1_kernel(
    const float* __restrict__ x, const float* __restrict__ w1,
    float* __restrict__ out) {
  int idx = blockIdx.x * 256 + threadIdx.x;   // 61440 = 240*256
  int oh = idx % 24; int t = idx / 24;
  int o  = t % 20;   int b = t / 20;
  const float* xb = x + b * 784;
  const float* wb = w1 + o * 25;
  float acc[24];
#pragma unroll
  for (int i = 0; i < 24; ++i) acc[i] = 0.f;
  for (int kh = 0; kh < 5; ++kh) {
    // x row: 28 floats, 112B-aligned
    float xr[28];
    const float4* xp = (const float4*)(xb + (oh + kh) * 28);
#pragma unroll
    for (int i = 0; i < 7; ++i) {
      float4 v = xp[i];
      xr[4*i] = v.x; xr[4*i+1] = v.y; xr[4*i+2] = v.z; xr[4*i+3] = v.w;
    }
    float wr[5];
#pragma unroll
    for (int i = 0; i < 5; ++i) wr[i] = wb[kh * 5 + i];
#pragma unroll
    for (int ow = 0; ow < 24; ++ow)
#pragma unroll
      for (int kw = 0; kw < 5; ++kw)
        acc[ow] += fabsf(xr[ow + kw] - wr[kw]);
  }
  float* op = out + (((size_t)b * 20 + o) * 24 + oh) * 24;
#pragma unroll
  for (int ow = 0; ow < 24; ++ow) op[ow] = -acc[ow];
}

// ---- BN partial sums: grid = C*slices blocks; atomicAdd into sums[2*C] -----
__global__ __launch_bounds__(256) void bn_partial_kernel(
    const float* __restrict__ h, int C, int HW4, int bPerSlice,
    float* __restrict__ sums) {
  const int c = blockIdx.x % C;
  const int slice = blockIdx.x / C;
  const int b0 = slice * bPerSlice;
  float s = 0.f, s2 = 0.f;
  for (int b = b0; b < b0 + bPerSlice; ++b) {
    const float4* hp = (const float4*)(h + (size_t)(b * C + c) * (HW4 * 4));
    for (int p = threadIdx.x; p < HW4; p += 256) {
      float4 v = hp[p];
      s  += v.x + v.y + v.z + v.w;
      s2 += v.x * v.x + v.y * v.y + v.z * v.z + v.w * v.w;
    }
  }
  __shared__ float ls[256], ls2[256];
  ls[threadIdx.x] = s; ls2[threadIdx.x] = s2;
  __syncthreads();
  for (int off = 128; off > 0; off >>= 1) {
    if (threadIdx.x < off) {
      ls[threadIdx.x]  += ls[threadIdx.x + off];
      ls2[threadIdx.x] += ls2[threadIdx.x + off];
    }
    __syncthreads();
  }
  if (threadIdx.x == 0) {
    atomicAdd(&sums[2 * c],     ls[0]);
    atomicAdd(&sums[2 * c + 1], ls2[0]);
  }
}

// ---- BN finalize + apply + 2x2 maxpool (normal layout out) -----------------
__global__ __launch_bounds__(256) void bn_pool_kernel(
    const float* __restrict__ h, const float* __restrict__ sums,
    const float* __restrict__ gamma, const float* __restrict__ beta,
    float* __restrict__ out, int C, int Hin, int Hout, float inv_n) {
  int idx = blockIdx.x * 256 + threadIdx.x;
  int pw = idx % Hout; int t = idx / Hout;
  int ph = t % Hout;   t /= Hout;
  int c  = t % C;      int b = t / C;
  float sm   = sums[2 * c];
  float s2   = sums[2 * c + 1];
  float mean = sm * inv_n;
  float var  = s2 * inv_n - mean * mean;
  float sc   = gamma[c] * rsqrtf(var + EPSBN);
  float bi   = beta[c] - mean * sc;
  const float* hp = h + ((b * C + c) * Hin + 2 * ph) * Hin + 2 * pw;
  float v0 = fmaf(sc, hp[0],       bi);
  float v1 = fmaf(sc, hp[1],       bi);
  float v2 = fmaf(sc, hp[Hin],     bi);
  float v3 = fmaf(sc, hp[Hin + 1], bi);
  out[idx] = fmaxf(fmaxf(v0, v1), fmaxf(v2, v3));
}

// ---- BN finalize + apply + 2x2 maxpool, TRANSPOSED out: featT[k][b] --------
__global__ __launch_bounds__(256) void bn_pool_t_kernel(
    const float* __restrict__ h, const float* __restrict__ sums,
    const float* __restrict__ gamma, const float* __restrict__ beta,
    float* __restrict__ outT, float inv_n) {   // h:[128,50,8,8] -> outT[800][128]
  int idx = blockIdx.x * 256 + threadIdx.x;    // 102400 = 400*256
  int pw = idx % 4; int t = idx / 4;
  int ph = t % 4;   t /= 4;
  int c  = t % 50;  int b = t / 50;
  float sm   = sums[2 * c];
  float s2   = sums[2 * c + 1];
  float mean = sm * inv_n;
  float var  = s2 * inv_n - mean * mean;
  float sc   = gamma[c] * rsqrtf(var + EPSBN);
  float bi   = beta[c] - mean * sc;
  const float* hp = h + ((b * 50 + c) * 8 + 2 * ph) * 8 + 2 * pw;
  float v0 = fmaf(sc, hp[0], bi);
  float v1 = fmaf(sc, hp[1], bi);
  float v2 = fmaf(sc, hp[8], bi);
  float v3 = fmaf(sc, hp[9], bi);
  int k = (c * 16 + ph * 4 + pw);
  outT[k * 128 + b] = fmaxf(fmaxf(v0, v1), fmaxf(v2, v3));
}

// ---- adder conv 2: h[128,20,12,12], w[50,20,5,5] -> [128,50,8,8] -----------
// thread = (b,o,oh), computes 8 outputs (full ow row).
__global__ __launch_bounds__(256) void adder2_kernel(
    const float* __restrict__ h, const float* __restrict__ w2,
    float* __restrict__ out) {
  int idx = blockIdx.x * 256 + threadIdx.x;   // 51200 = 200*256
  int oh = idx % 8; int t = idx / 8;
  int o  = t % 50;  int b = t / 50;
  const float* hb = h + (size_t)b * (20 * 144);
  const float* wb = w2 + o * 500;
  float acc[8];
#pragma unroll
  for (int i = 0; i < 8; ++i) acc[i] = 0.f;
  for (int c = 0; c < 20; ++c) {
    const float* hc = hb + c * 144;
    const float* wc = wb + c * 25;
#pragma unroll
    for (int kh = 0; kh < 5; ++kh) {
      // h row: 12 floats, 48B-aligned
      float hr[12];
      const float4* hp = (const float4*)(hc + (oh + kh) * 12);
#pragma unroll
      for (int i = 0; i < 3; ++i) {
        float4 v = hp[i];
        hr[4*i] = v.x; hr[4*i+1] = v.y; hr[4*i+2] = v.z; hr[4*i+3] = v.w;
      }
      float wr[5];
#pragma unroll
      for (int i = 0; i < 5; ++i) wr[i] = wc[kh * 5 + i];
#pragma unroll
      for (int ow = 0; ow < 8; ++ow)
#pragma unroll
        for (int kw = 0; kw < 5; ++kw)
          acc[ow] += fabsf(hr[ow + kw] - wr[kw]);
    }
  }
  float* op = out + (((size_t)b * 50 + o) * 8 + oh) * 8;
#pragma unroll
  for (int ow = 0; ow < 8; ++ow) op[ow] = -acc[ow];
}

// ---- fc1 + relu: featT[800][128] x w[500,800] -> hid[128][512] -------------
// thread = (j,b); lane = b -> coalesced featT loads; w row wave-uniform.
__global__ __launch_bounds__(256) void fc1_kernel(
    const float* __restrict__ featT, const float* __restrict__ w1,
    const float* __restrict__ b1, float* __restrict__ hid) {
  int idx = blockIdx.x * 256 + threadIdx.x;   // 64000 = 250*256
  int b = idx & 127;
  int j = idx >> 7;                           // 0..499
  const float* wr = w1 + j * 800;
  const float* fb = featT + b;
  float acc = b1[j];
  for (int k = 0; k < 800; k += 4) {
    float4 w4 = *(const float4*)(wr + k);
    acc += fb[(k    ) * 128] * w4.x + fb[(k + 1) * 128] * w4.y +
           fb[(k + 2) * 128] * w4.z + fb[(k + 3) * 128] * w4.w;
  }
  hid[b * 512 + j] = fmaxf(acc, 0.f);
}

// ---- fc2 + bias + softmax: hid[128][512] x w[10,500] -> out[128][10] -------
__global__ __launch_bounds__(64) void fc2_softmax_kernel(
    const float* __restrict__ hid, const float* __restrict__ w2,
    const float* __restrict__ b2, float* __restrict__ out) {
  const int b = blockIdx.x, lane = threadIdx.x;
  const float* hb = hid + b * 512;
  __shared__ float logit[16];
  for (int j = 0; j < 10; ++j) {
    const float* wr = w2 + j * 500;
    float acc = 0.f;
    for (int k = lane; k < 500; k += 64) acc += hb[k] * wr[k];
#pragma unroll
    for (int off = 32; off > 0; off >>= 1) acc += __shfl_down(acc, off);
    if (lane == 0) logit[j] = acc + b2[j];
  }
  __syncthreads();
  if (lane == 0) {
    float m = logit[0];
    for (int j = 1; j < 10; ++j) m = fmaxf(m, logit[j]);
    float s = 0.f, e[10];
    for (int j = 0; j < 10; ++j) { e[j] = __expf(logit[j] - m); s += e[j]; }
    float inv = 1.f / s;
    for (int j = 0; j < 10; ++j) out[b * 10 + j] = e[j] * inv;
  }
}

extern "C" void kernel_launch(void* const* d_in, const int* in_sizes, int n_in,
                              void* d_out, int out_size, void* d_ws, size_t ws_size,
                              hipStream_t stream) {
  const float* x   = (const float*)d_in[0];   // [128,1,28,28]
  const float* w1  = (const float*)d_in[1];   // [20,1,5,5]
  const float* g1  = (const float*)d_in[2];   // [20]
  const float* be1 = (const float*)d_in[3];   // [20]
  const float* w2  = (const float*)d_in[4];   // [50,20,5,5]
  const float* g2  = (const float*)d_in[5];   // [50]
  const float* be2 = (const float*)d_in[6];   // [50]
  const float* fw1 = (const float*)d_in[7];   // [500,800]
  const float* fb1 = (const float*)d_in[8];   // [500]
  const float* fw2 = (const float*)d_in[9];   // [10,500]
  const float* fb2 = (const float*)d_in[10];  // [10]
  float* out = (float*)d_out;

  // workspace layout (floats); regions inside h1 reused once h1 is dead.
  float* ws    = (float*)d_ws;
  float* h1    = ws;               // [0, 1474560)        128*20*24*24
  float* h1p   = ws + 1474560;     // [1474560, 1843200)  128*20*12*12
  float* h2    = ws;               // reuse: [0, 409600)  128*50*8*8
  float* featT = ws + 409600;      // [409600, 512000)    800*128 (dead h1)
  float* hid   = ws + 512000;      // [512000, 577536)    128*512 (dead h1)
  float* sums1 = ws + 1843200;     // [2*20]
  float* sums2 = sums1 + 40;       // [2*50]

  hipMemsetAsync(sums1, 0, 140 * sizeof(float), stream);

  adder1_kernel<<<240, 256, 0, stream>>>(x, w1, h1);
  bn_partial_kernel<<<20 * 16, 256, 0, stream>>>(h1, 20, 144, 8, sums1);
  bn_pool_kernel<<<1440, 256, 0, stream>>>(h1, sums1, g1, be1, h1p, 20, 24, 12,
                                           1.f / (B_N * 576));
  adder2_kernel<<<200, 256, 0, stream>>>(h1p, w2, h2);
  bn_partial_kernel<<<50 * 8, 256, 0, stream>>>(h2, 50, 16, 16, sums2);
  bn_pool_t_kernel<<<400, 256, 0, stream>>>(h2, sums2, g2, be2, featT,
                                            1.f / (B_N * 64));
  fc1_kernel<<<250, 256, 0, stream>>>(featT, fw1, fb1, hid);
  fc2_softmax_kernel<<<128, 64, 0, stream>>>(hid, fw2, fb2, out);
}